// Round 13
// baseline (183.306 us; speedup 1.0000x reference)
//
#include <hip/hip_runtime.h>

#define AS1 __attribute__((address_space(1)))
#define AS3 __attribute__((address_space(3)))

typedef float    f32x4  __attribute__((ext_vector_type(4)));
typedef __bf16   bf16x8 __attribute__((ext_vector_type(8)));
typedef __bf16   bf16x4 __attribute__((ext_vector_type(4)));
typedef unsigned int u32x4 __attribute__((ext_vector_type(4)));

static constexpr int SEQ = 4096, NBATCH = 2, DMODEL = 1024, NHEADS = 16, HDIM = 64;
static constexpr int LHEADS = 8, LDIM = 512, NLAT = 64, WIN = 256;
static constexpr int BSROWS = NBATCH * SEQ; // 8192
static constexpr int QKVN = 3584;           // fused [Q|K|V|GQ] column count
static constexpr int KOFF = 1024, VOFF = 2048, GQOFF = 3072;

// ---------------- ONE prep dispatch: cvt+pool + 8 weight transposes + xpool pad-zero ----------------
struct TJ { const float* in; __bf16* out; int K; int N; };
struct TJ8 { TJ j[8]; };
__global__ __launch_bounds__(256) void prep_all(const float* __restrict__ x,
                                                __bf16* __restrict__ xb,
                                                __bf16* __restrict__ xpool, TJ8 jobs) {
    __shared__ float tbuf[32][33];
    int bid = blockIdx.x, t = threadIdx.x;
    if (bid < 512) {
        int bn = bid >> 2;
        int c  = (bid & 3) * 256 + t;
        const float* p = x + (size_t)bn * 64 * 1024 + c;
        __bf16* q = xb + (size_t)bn * 64 * 1024 + c;
        float s = 0.f;
        #pragma unroll 8
        for (int j = 0; j < 64; ++j) {
            float v = p[(size_t)j * 1024];
            q[(size_t)j * 1024] = (__bf16)v;
            s += v;
        }
        xpool[(size_t)bn * 1024 + c] = (__bf16)(s * 0.015625f);
    } else if (bid < 8704) {
        int ti = bid - 512;
        TJ jb = jobs.j[ti >> 10];
        int rem = ti & 1023;
        int k0 = (rem >> 5) * 32, n0 = (rem & 31) * 32;
        if (k0 >= jb.K || n0 >= jb.N) return;
        int tx = t & 31, ty = t >> 5; // (32, 8)
        #pragma unroll
        for (int i = ty; i < 32; i += 8) tbuf[i][tx] = jb.in[(size_t)(k0 + i) * jb.N + n0 + tx];
        __syncthreads();
        #pragma unroll
        for (int i = ty; i < 32; i += 8) jb.out[(size_t)(n0 + i) * jb.K + k0 + tx] = (__bf16)tbuf[tx][i];
    } else {
        int zi = bid - 8704;                 // 0..31
        size_t idx = ((size_t)zi * 256 + t) * 16;
        u32x4 z = {0u, 0u, 0u, 0u};
        *(u32x4*)(xpool + 128 * 1024 + idx)     = z;
        *(u32x4*)(xpool + 128 * 1024 + idx + 8) = z;
    }
}

// ---------------- 256x256 8-phase GEMM (T2+T3+T4+T5) + GKV side-row ----------------
// (verified r7-r12; conflict-free swizzle byte^=(row&7)<<4; fused V-transpose epilogue)
#define BAR() do { __builtin_amdgcn_sched_barrier(0); __builtin_amdgcn_s_barrier(); \
                   __builtin_amdgcn_sched_barrier(0); } while (0)
#define LGK0() do { asm volatile("s_waitcnt lgkmcnt(0)" ::: "memory"); \
                    __builtin_amdgcn_sched_barrier(0); } while (0)
#define VMC(n) do { asm volatile("s_waitcnt vmcnt(" #n ")" ::: "memory"); \
                    __builtin_amdgcn_sched_barrier(0); } while (0)
#define STG(gp, regionbase, rowbase, ktc) do { \
    int row_ = (rowbase) + (t >> 3); \
    int tc_ = (t & 7) ^ ((t >> 3) & 7); \
    __builtin_amdgcn_global_load_lds( \
        (const AS1 void*)((gp) + (size_t)row_ * K + (ktc) + tc_ * 8), \
        (AS3 void*)(lds + (regionbase) + (rowbase) * 128 + w * 1024), 16, 0, 0); \
} while (0)
#define LOADA(buf, qm) do { \
    _Pragma("unroll") for (int ai_ = 0; ai_ < 4; ++ai_) \
    _Pragma("unroll") for (int ks_ = 0; ks_ < 2; ++ks_) \
        a[ai_][ks_] = *(const bf16x8*)(lds + ((((buf) * 65536) + \
            (wm * 128 + (qm) * 64 + ai_ * 16 + l15) * 128 + ks_ * 64 + l4 * 16) ^ rswz)); \
} while (0)
#define LOADB2(buf, half) do { \
    _Pragma("unroll") for (int j_ = 0; j_ < 2; ++j_) \
    _Pragma("unroll") for (int ks_ = 0; ks_ < 2; ++ks_) \
        b2[j_][ks_] = *(const bf16x8*)(lds + ((((buf) * 65536 + 32768) + \
            (wn * 64 + ((half) * 2 + j_) * 16 + l15) * 128 + ks_ * 64 + l4 * 16) ^ rswz)); \
} while (0)
#define MFMA_PH(qm, half) do { \
    __builtin_amdgcn_s_setprio(1); \
    _Pragma("unroll") for (int ai_ = 0; ai_ < 4; ++ai_) \
    _Pragma("unroll") for (int j_ = 0; j_ < 2; ++j_) { \
        f32x4 c_ = acc[(qm) * 4 + ai_][(half) * 2 + j_]; \
        c_ = __builtin_amdgcn_mfma_f32_16x16x32_bf16(a[ai_][0], b2[j_][0], c_, 0, 0, 0); \
        c_ = __builtin_amdgcn_mfma_f32_16x16x32_bf16(a[ai_][1], b2[j_][1], c_, 0, 0, 0); \
        acc[(qm) * 4 + ai_][(half) * 2 + j_] = c_; \
    } \
    __builtin_amdgcn_s_setprio(0); \
} while (0)

__global__ __launch_bounds__(512, 2) void gemm256_bf16(
    const __bf16* __restrict__ A, const __bf16* __restrict__ Bt,
    int M, int N, int K, __bf16* __restrict__ outb, __bf16* __restrict__ Vt,
    const __bf16* __restrict__ A2, const __bf16* __restrict__ B2,
    __bf16* __restrict__ out2) {
    __shared__ char lds[131072];
    const int t = threadIdx.x, w = t >> 6, l = t & 63;
    const int wm = w >> 2, wn = w & 3;
    const int l15 = l & 15, l4 = l >> 4;
    const int NT = K >> 6;
    const int rswz = (l15 & 7) << 4;

    const __bf16* Ab; const __bf16* Bb; __bf16* outp; int Nout, m0, n0; bool doVt;
    if (blockIdx.y == 14) {
        if (blockIdx.x >= 4) return;      // whole block exits; no barrier hazard
        m0 = 0; n0 = blockIdx.x * 256;
        Ab = A2; Bb = B2 + (size_t)n0 * K;
        outp = out2; Nout = 1024; doVt = false;
    } else {
        m0 = blockIdx.x * 256; n0 = blockIdx.y * 256;
        Ab = A + (size_t)m0 * K; Bb = Bt + (size_t)n0 * K;
        outp = outb; Nout = N; doVt = (n0 >= VOFF && n0 < GQOFF);
    }

    f32x4 acc[8][4];
    #pragma unroll
    for (int i = 0; i < 8; ++i)
        #pragma unroll
        for (int j = 0; j < 4; ++j) acc[i][j] = (f32x4){0.f, 0.f, 0.f, 0.f};
    bf16x8 a[4][2], b2[2][2];

    STG(Ab, 0, 0, 0);        STG(Ab, 0, 128, 0);
    STG(Ab, 0, 64, 0);       STG(Ab, 0, 192, 0);
    STG(Bb, 32768, 0, 0);    STG(Bb, 32768, 64, 0);
    STG(Bb, 32768, 128, 0);  STG(Bb, 32768, 192, 0);
    STG(Ab, 65536, 0, 64);   STG(Ab, 65536, 128, 64);
    VMC(2); BAR();

    int it = 0;
    for (; it + 3 < NT; it += 2) {
        const int kt1 = (it + 1) << 6, kt2 = (it + 2) << 6, kt3 = (it + 3) << 6;
        LOADA(0, 0); LOADB2(0, 0);
        STG(Ab, 65536, 64, kt1); STG(Ab, 65536, 192, kt1);
        BAR(); LGK0(); MFMA_PH(0, 0); BAR();
        LOADB2(0, 1);
        STG(Bb, 98304, 0, kt1); STG(Bb, 98304, 64, kt1);
        BAR(); LGK0(); MFMA_PH(0, 1); BAR();
        LOADA(0, 1); LOADB2(0, 0);
        STG(Bb, 98304, 128, kt1); STG(Bb, 98304, 192, kt1);
        BAR(); LGK0(); MFMA_PH(1, 0); BAR();
        LOADB2(0, 1);
        STG(Ab, 0, 0, kt2); STG(Ab, 0, 128, kt2);
        BAR(); LGK0(); MFMA_PH(1, 1); VMC(2); BAR();
        LOADA(1, 0); LOADB2(1, 0);
        STG(Ab, 0, 64, kt2); STG(Ab, 0, 192, kt2);
        BAR(); LGK0(); MFMA_PH(0, 0); BAR();
        LOADB2(1, 1);
        STG(Bb, 32768, 0, kt2); STG(Bb, 32768, 64, kt2);
        BAR(); LGK0(); MFMA_PH(0, 1); BAR();
        LOADA(1, 1); LOADB2(1, 0);
        STG(Bb, 32768, 128, kt2); STG(Bb, 32768, 192, kt2);
        BAR(); LGK0(); MFMA_PH(1, 0); BAR();
        LOADB2(1, 1);
        STG(Ab, 65536, 0, kt3); STG(Ab, 65536, 128, kt3);
        BAR(); LGK0(); MFMA_PH(1, 1); VMC(2); BAR();
    }
    {
        const int kt1 = (it + 1) << 6;
        LOADA(0, 0); LOADB2(0, 0);
        STG(Ab, 65536, 64, kt1); STG(Ab, 65536, 192, kt1);
        BAR(); LGK0(); MFMA_PH(0, 0); BAR();
        LOADB2(0, 1);
        STG(Bb, 98304, 0, kt1); STG(Bb, 98304, 64, kt1);
        BAR(); LGK0(); MFMA_PH(0, 1); BAR();
        LOADA(0, 1); LOADB2(0, 0);
        STG(Bb, 98304, 128, kt1); STG(Bb, 98304, 192, kt1);
        BAR(); LGK0(); MFMA_PH(1, 0); BAR();
        LOADB2(0, 1);
        BAR(); LGK0(); MFMA_PH(1, 1); VMC(0); BAR();
        LOADA(1, 0); LOADB2(1, 0);
        BAR(); LGK0(); MFMA_PH(0, 0); BAR();
        LOADB2(1, 1);
        BAR(); LGK0(); MFMA_PH(0, 1); BAR();
        LOADA(1, 1); LOADB2(1, 0);
        BAR(); LGK0(); MFMA_PH(1, 0); BAR();
        LOADB2(1, 1);
        LGK0(); MFMA_PH(1, 1);
    }

    int cr = l4 * 4, cc = l15;
    if (doVt) {
        #pragma unroll
        for (int mi = 0; mi < 8; ++mi) {
            #pragma unroll
            for (int ni = 0; ni < 4; ++ni) {
                int vcol = (n0 - VOFF) + wn * 64 + ni * 16 + cc;
                int row0 = m0 + wm * 128 + mi * 16 + cr;
                int bb = row0 >> 12, ss = row0 & 4095;
                bf16x4 pk;
                #pragma unroll
                for (int r = 0; r < 4; ++r) pk[r] = (__bf16)acc[mi][ni][r];
                *(bf16x4*)(Vt + ((size_t)bb * DMODEL + vcol) * SEQ + ss) = pk;
            }
        }
    } else {
        #pragma unroll
        for (int mi = 0; mi < 8; ++mi) {
            #pragma unroll
            for (int ni = 0; ni < 4; ++ni) {
                int col = n0 + wn * 64 + ni * 16 + cc;
                #pragma unroll
                for (int r = 0; r < 4; ++r) {
                    int row = m0 + wm * 128 + mi * 16 + cr + r;
                    outp[(size_t)row * Nout + col] = (__bf16)acc[mi][ni][r];
                }
            }
        }
    }
}
#undef LOADA
#undef LOADB2
#undef MFMA_PH

// ---------------- 128x256-tile 2-phase/K-tile pipelined GEMM (tail-free for N=1024) ----------------
// r13: 4-phase -> 2-phase (16 MFMA per barrier-pair, parity with gemm256's density).
// 3-buffer rotation + counted vmcnt(6) UNCHANGED (hazards are tile-granular).
// P1: all 4 A-frags + B-half-0 (12 ds_reads) + 3 STG -> 16 MFMA.
// P2: B-half-1 (4 ds_reads) + 3 STG -> 16 MFMA + vmcnt(6).
#define LOADA3F(base) do { \
    _Pragma("unroll") for (int ai_ = 0; ai_ < 4; ++ai_) \
    _Pragma("unroll") for (int ks_ = 0; ks_ < 2; ++ks_) \
        a[ai_][ks_] = *(const bf16x8*)(lds + (((base) + \
            (wm2 * 64 + ai_ * 16 + l15) * 128 + ks_ * 64 + l4 * 16) ^ rswz)); \
} while (0)
#define LOADB3(base, nh) do { \
    _Pragma("unroll") for (int j_ = 0; j_ < 2; ++j_) \
    _Pragma("unroll") for (int ks_ = 0; ks_ < 2; ++ks_) \
        b2[j_][ks_] = *(const bf16x8*)(lds + (((base) + 16384 + \
            (wn * 64 + (nh) * 32 + j_ * 16 + l15) * 128 + ks_ * 64 + l4 * 16) ^ rswz)); \
} while (0)
#define MFMA_P3N(nh) do { \
    __builtin_amdgcn_s_setprio(1); \
    _Pragma("unroll") for (int ai_ = 0; ai_ < 4; ++ai_) \
    _Pragma("unroll") for (int j_ = 0; j_ < 2; ++j_) { \
        f32x4 c_ = acc[ai_][(nh) * 2 + j_]; \
        c_ = __builtin_amdgcn_mfma_f32_16x16x32_bf16(a[ai_][0], b2[j_][0], c_, 0, 0, 0); \
        c_ = __builtin_amdgcn_mfma_f32_16x16x32_bf16(a[ai_][1], b2[j_][1], c_, 0, 0, 0); \
        acc[ai_][(nh) * 2 + j_] = c_; \
    } \
    __builtin_amdgcn_s_setprio(0); \
} while (0)

template <bool EPI, bool OUTBF>
__global__ __launch_bounds__(512, 1) void gemm128n(
    const __bf16* __restrict__ A, const __bf16* __restrict__ Bt,
    int M, int N, int K,
    __bf16* __restrict__ outb, float* __restrict__ outf,
    const __bf16* __restrict__ lcl, const float* __restrict__ grb) {
    __shared__ char lds[147456];    // 3 x (16KB A + 32KB B)
    const int t = threadIdx.x, w = t >> 6, l = t & 63;
    const int wm2 = w >> 2, wn = w & 3;
    const int l15 = l & 15, l4 = l >> 4;
    const int m0 = blockIdx.x * 128, n0 = blockIdx.y * 256;
    const int NT = K >> 6;
    const int rswz = (l15 & 7) << 4;

    f32x4 acc[4][4];
    #pragma unroll
    for (int i = 0; i < 4; ++i)
        #pragma unroll
        for (int j = 0; j < 4; ++j) acc[i][j] = (f32x4){0.f, 0.f, 0.f, 0.f};
    bf16x8 a[4][2], b2[2][2];

    const __bf16* Ab = A + (size_t)m0 * K;
    const __bf16* Bb = Bt + (size_t)n0 * K;

    // prologue: stage tile0 -> buf0, tile1 -> buf1 (6 loads each); wait tile0 (vmcnt 6)
    STG(Ab, 0, 0, 0);      STG(Ab, 0, 64, 0);
    STG(Bb, 16384, 0, 0);  STG(Bb, 16384, 64, 0);
    STG(Bb, 16384, 128, 0); STG(Bb, 16384, 192, 0);
    STG(Ab, 49152, 0, 64);      STG(Ab, 49152, 64, 64);
    STG(Bb, 65536, 0, 64);  STG(Bb, 65536, 64, 64);
    STG(Bb, 65536, 128, 64); STG(Bb, 65536, 192, 64);
    VMC(6); BAR();

    int cb = 0, nb = 98304;   // current buf base; stage-target buf base ((it+2)%3)
    for (int it = 0; it + 2 < NT; ++it) {
        const int kt2 = (it + 2) << 6;
        // P1
        LOADA3F(cb); LOADB3(cb, 0);
        STG(Ab, nb, 0, kt2); STG(Ab, nb, 64, kt2); STG(Bb, nb + 16384, 0, kt2);
        BAR(); LGK0(); MFMA_P3N(0); BAR();
        // P2
        LOADB3(cb, 1);
        STG(Bb, nb + 16384, 64, kt2); STG(Bb, nb + 16384, 128, kt2); STG(Bb, nb + 16384, 192, kt2);
        BAR(); LGK0(); MFMA_P3N(1); VMC(6); BAR();
        cb = (cb == 98304) ? 0 : cb + 49152;
        nb = (nb == 98304) ? 0 : nb + 49152;
    }
    // tail tile NT-2: no stages; drain at P2
    {
        LOADA3F(cb); LOADB3(cb, 0);
        BAR(); LGK0(); MFMA_P3N(0); BAR();
        LOADB3(cb, 1);
        BAR(); LGK0(); MFMA_P3N(1); VMC(0); BAR();
        cb = (cb == 98304) ? 0 : cb + 49152;
    }
    // tail tile NT-1
    {
        LOADA3F(cb); LOADB3(cb, 0);
        BAR(); LGK0(); MFMA_P3N(0); BAR();
        LOADB3(cb, 1);
        LGK0(); MFMA_P3N(1);
    }

    // epilogue (verified C/D mapping + EPI combine)
    int cr = l4 * 4, cc = l15;
    #pragma unroll
    for (int mi = 0; mi < 4; ++mi) {
        #pragma unroll
        for (int ni = 0; ni < 4; ++ni) {
            int col = n0 + wn * 64 + ni * 16 + cc;
            #pragma unroll
            for (int r = 0; r < 4; ++r) {
                int row = m0 + wm2 * 64 + mi * 16 + cr + r;
                float v = acc[mi][ni][r];
                if constexpr (EPI) {
                    v = (float)lcl[(size_t)row * 1024 + col] +
                        grb[(size_t)row * 16 + (col >> 6)] * v;
                }
                if constexpr (OUTBF) outb[(size_t)row * N + col] = (__bf16)v;
                else                 outf[(size_t)row * N + col] = v;
            }
        }
    }
}
#undef BAR
#undef LGK0
#undef VMC
#undef STG
#undef LOADA3F
#undef LOADB3
#undef MFMA_P3N

// ---------------- fused attention: ONE dispatch for local + latent (verified r11/r12) ----------------
// r13: launch_bounds (256,3) — 32KB LDS allows 5 blocks/CU, VGPR was the cap; 3 blocks/CU now.
__global__ __launch_bounds__(256, 3) void attn_fused(
    const __bf16* __restrict__ QKVG, const __bf16* __restrict__ Vt,
    const __bf16* __restrict__ GKV,
    const float* __restrict__ glw, const float* __restrict__ grw,
    __bf16* __restrict__ outl, float* __restrict__ grbuf,
    __bf16* __restrict__ rem) {
    __shared__ alignas(16) char smem[32768];
    int t = threadIdx.x, w = t >> 6, l = t & 63;
    int l15 = l & 15, l4 = l >> 4;
    int b = blockIdx.z;
    f32x4 zero = {0.f, 0.f, 0.f, 0.f};

    if (blockIdx.y < 16) {
        // ======== local sliding-window attention (K-direct + V-direct) ========
        int blk = blockIdx.x, h = blockIdx.y;
        char* sPb = smem;

        bf16x8 qf[4][2];
        long qbase = (long)b * SEQ + blk * 256 + 64 * w;
        #pragma unroll
        for (int qq = 0; qq < 4; ++qq)
            #pragma unroll
            for (int ks = 0; ks < 2; ++ks)
                qf[qq][ks] = *(const bf16x8*)(QKVG + (size_t)(qbase + qq * 16 + l15) * QKVN
                                              + h * 64 + ks * 32 + l4 * 8);

        float dlp[4], drp[4];
        #pragma unroll
        for (int qq = 0; qq < 4; ++qq) {
            float dl = 0.f, dr = 0.f;
            #pragma unroll
            for (int ks = 0; ks < 2; ++ks) {
                const float* gp = glw + h * 64 + ks * 32 + l4 * 8;
                const float* rp = grw + h * 64 + ks * 32 + l4 * 8;
                #pragma unroll
                for (int j = 0; j < 8; ++j) {
                    float qv = (float)qf[qq][ks][j];
                    dl += qv * gp[j];
                    dr += qv * rp[j];
                }
            }
            dlp[qq] = dl; drp[qq] = dr;
        }
        float glv[4], grv[4];
        #pragma unroll
        for (int qq = 0; qq < 4; ++qq) {
            float dl = dlp[qq] + __shfl_xor(dlp[qq], 16);
            dl += __shfl_xor(dl, 32);
            float dr = drp[qq] + __shfl_xor(drp[qq], 16);
            dr += __shfl_xor(dr, 32);
            glv[qq] = 1.f / (1.f + __expf(-dl));
            grv[qq] = 1.f / (1.f + __expf(-dr));
        }
        if (l4 == 0) {
            #pragma unroll
            for (int qq = 0; qq < 4; ++qq)
                grbuf[(size_t)(qbase + qq * 16 + l15) * 16 + h] = grv[qq];
        }

        f32x4 acc[4][4];
        #pragma unroll
        for (int a2 = 0; a2 < 4; ++a2)
            #pragma unroll
            for (int d = 0; d < 4; ++d) acc[a2][d] = zero;
        float psum[4] = {0.f, 0.f, 0.f, 0.f};

        char* sPw = sPb + w * 4096;
        int nsteps = (w == 3) ? 10 : 11;
        int kk0 = 64 * w;
        long g0 = (long)b * SEQ + (long)(blk - 1) * WIN;
        const __bf16* vtb = Vt + (size_t)b * DMODEL * SEQ + (size_t)(h * 64) * SEQ;

        for (int stp = 0; stp < nsteps; ++stp) {
            int kk = kk0 + 32 * stp;
            f32x4 sacc[2][4];
            #pragma unroll
            for (int kt2 = 0; kt2 < 2; ++kt2) {
                int krow = kk + kt2 * 16 + l15;
                long kgrow = g0 + krow;
                if (blk == 0 && krow < 256) kgrow = (long)b * SEQ;  // clamp; masked anyway
                const __bf16* kp = QKVG + (size_t)kgrow * QKVN + KOFF + h * 64;
                bf16x8 af0 = *(const bf16x8*)(kp + l4 * 8);
                bf16x8 af1 = *(const bf16x8*)(kp + 32 + l4 * 8);
                #pragma unroll
                for (int qq = 0; qq < 4; ++qq) {
                    f32x4 s = __builtin_amdgcn_mfma_f32_16x16x32_bf16(af0, qf[qq][0], zero, 0, 0, 0);
                    sacc[kt2][qq] = __builtin_amdgcn_mfma_f32_16x16x32_bf16(af1, qf[qq][1], s, 0, 0, 0);
                }
            }
            #pragma unroll
            for (int qq = 0; qq < 4; ++qq) {
                int qloc = 64 * w + qq * 16 + l15;
                int prow = qq * 16 + l15;
                #pragma unroll
                for (int kt2 = 0; kt2 < 2; ++kt2) {
                    int jb = kk + kt2 * 16 + l4 * 4;
                    bf16x4 pb;
                    #pragma unroll
                    for (int r = 0; r < 4; ++r) {
                        int jw = jb + r;
                        bool act = (jw > qloc) && (jw <= qloc + 256) && (blk > 0 || jw >= 256);
                        float pv = act ? __expf(sacc[kt2][qq][r] * 0.125f) : 0.f;
                        psum[qq] += pv;
                        pb[r] = (__bf16)pv;
                    }
                    *(bf16x4*)(sPw + prow * 64 + ((kt2 * 32 + l4 * 8) ^ ((prow & 3) << 4))) = pb;
                }
            }
            int kglob = (blk - 1) * WIN + kk + l4 * 8;
            if (kglob < 0) kglob = 0;
            bf16x8 pa[4], bv[4];
            #pragma unroll
            for (int qq = 0; qq < 4; ++qq) {
                int prow = qq * 16 + l15;
                pa[qq] = *(const bf16x8*)(sPw + prow * 64 + ((l4 * 16) ^ ((prow & 3) << 4)));
            }
            #pragma unroll
            for (int dt = 0; dt < 4; ++dt)
                bv[dt] = *(const bf16x8*)(vtb + (size_t)(dt * 16 + l15) * SEQ + kglob);
            #pragma unroll
            for (int qq = 0; qq < 4; ++qq)
                #pragma unroll
                for (int dt = 0; dt < 4; ++dt)
                    acc[qq][dt] = __builtin_amdgcn_mfma_f32_16x16x32_bf16(pa[qq], bv[dt], acc[qq][dt], 0, 0, 0);
        }

        float cmb[4];
        #pragma unroll
        for (int qq = 0; qq < 4; ++qq) {
            float s = psum[qq] + __shfl_xor(psum[qq], 16);
            s += __shfl_xor(s, 32);
            cmb[qq] = glv[qq] / s;
        }
        #pragma unroll
        for (int qq = 0; qq < 4; ++qq) {
            #pragma unroll
            for (int r = 0; r < 4; ++r) {
                float sc = __shfl(cmb[qq], l4 * 4 + r, 64);
                size_t row = (size_t)(qbase + qq * 16 + l4 * 4 + r);
                __bf16* op = outl + row * DMODEL + h * 64 + l15;
                #pragma unroll
                for (int dt = 0; dt < 4; ++dt)
                    op[dt * 16] = (__bf16)(acc[qq][dt][r] * sc);
            }
        }
    } else {
        // ======== latent (remote) attention (verified r4-r12; GKV merged stride 1024) ========
        int sb = blockIdx.x, lh = blockIdx.y - 16;
        char* sK  = smem;
        char* sVt = smem + 8192;
        char* sPb = smem + 16384;

        bf16x8 qf[4][2];
        long qbase = (long)b * SEQ + sb * 256 + 64 * w;
        #pragma unroll
        for (int qq = 0; qq < 4; ++qq)
            #pragma unroll
            for (int ks = 0; ks < 2; ++ks)
                qf[qq][ks] = *(const bf16x8*)(QKVG + (size_t)(qbase + qq * 16 + l15) * QKVN
                                              + GQOFF + lh * 64 + ks * 32 + l4 * 8);

        #pragma unroll
        for (int rep = 0; rep < 2; ++rep) {
            int ci = rep * 256 + t;
            int row = ci >> 3, c8 = (ci & 7) * 8;
            u32x4 kv = *(const u32x4*)(GKV + (size_t)(b * 64 + row) * 1024 + lh * 64 + c8);
            *(u32x4*)(sK + row * 128 + ((c8 * 2) ^ ((row & 7) << 4))) = kv;
        }
        #pragma unroll
        for (int rep = 0; rep < 16; ++rep) {
            int idx = rep * 256 + t;
            int d = idx & 63, n = idx >> 6;
            __bf16 v = GKV[(size_t)(b * 64 + n) * 1024 + 512 + lh * 64 + d];
            *(__bf16*)(sVt + d * 128 + ((n * 2) ^ ((d & 7) << 4))) = v;
        }
        __syncthreads();

        f32x4 acc[4][4];
        #pragma unroll
        for (int a2 = 0; a2 < 4; ++a2)
            #pragma unroll
            for (int d = 0; d < 4; ++d) acc[a2][d] = zero;
        float psum[4] = {0.f, 0.f, 0.f, 0.f};

        char* sPw = sPb + w * 4096;
        int qloc0 = sb * 256 + 64 * w;

        #pragma unroll
        for (int stp = 0; stp < 2; ++stp) {
            int kk = 32 * stp;
            f32x4 sacc[2][4];
            #pragma unroll
            for (int kt2 = 0; kt2 < 2; ++kt2) {
                int krow = kk + kt2 * 16 + l15;
                int swz = (krow & 7) << 4;
                bf16x8 af0 = *(const bf16x8*)(sK + krow * 128 + ((l4 * 16) ^ swz));
                bf16x8 af1 = *(const bf16x8*)(sK + krow * 128 + ((64 + l4 * 16) ^ swz));
                #pragma unroll
                for (int qq = 0; qq < 4; ++qq) {
                    f32x4 s = __builtin_amdgcn_mfma_f32_16x16x32_bf16(af0, qf[qq][0], zero, 0, 0, 0);
                    sacc[kt2][qq] = __builtin_amdgcn_mfma_f32_16x16x32_bf16(af1, qf[qq][1], s, 0, 0, 0);
                }
            }
            #pragma unroll
            for (int qq = 0; qq < 4; ++qq) {
                int qdv = (qloc0 + qq * 16 + l15) >> 6;
                int prow = qq * 16 + l15;
                #pragma unroll
                for (int kt2 = 0; kt2 < 2; ++kt2) {
                    int nb = kk + kt2 * 16 + l4 * 4;
                    bf16x4 pb;
                    #pragma unroll
                    for (int r = 0; r < 4; ++r) {
                        int n = nb + r;
                        float pv = (n <= qdv) ? __expf(sacc[kt2][qq][r] * 0.125f) : 0.f;
                        psum[qq] += pv;
                        pb[r] = (__bf16)pv;
                    }
                    *(bf16x4*)(sPw + prow * 64 + ((kt2 * 32 + l4 * 8) ^ ((prow & 3) << 4))) = pb;
                }
            }
            bf16x8 pa[4], bv[4];
            #pragma unroll
            for (int qq = 0; qq < 4; ++qq) {
                int prow = qq * 16 + l15;
                pa[qq] = *(const bf16x8*)(sPw + prow * 64 + ((l4 * 16) ^ ((prow & 3) << 4)));
            }
            #pragma unroll
            for (int dt = 0; dt < 4; ++dt) {
                int d = dt * 16 + l15;
                bv[dt] = *(const bf16x8*)(sVt + d * 128 + ((kk * 2 + l4 * 16) ^ ((d & 7) << 4)));
            }
            #pragma unroll
            for (int qq = 0; qq < 4; ++qq)
                #pragma unroll
                for (int dt = 0; dt < 4; ++dt)
                    acc[qq][dt] = __builtin_amdgcn_mfma_f32_16x16x32_bf16(pa[qq], bv[dt], acc[qq][dt], 0, 0, 0);
        }

        float cmb[4];
        #pragma unroll
        for (int qq = 0; qq < 4; ++qq) {
            float s = psum[qq] + __shfl_xor(psum[qq], 16);
            s += __shfl_xor(s, 32);
            cmb[qq] = 1.f / s;
        }
        #pragma unroll
        for (int qq = 0; qq < 4; ++qq) {
            #pragma unroll
            for (int r = 0; r < 4; ++r) {
                float sc = __shfl(cmb[qq], l4 * 4 + r, 64);
                size_t row = (size_t)(qbase + qq * 16 + l4 * 4 + r);
                __bf16* op = rem + row * LDIM + lh * 64 + l15;
                #pragma unroll
                for (int dt = 0; dt < 4; ++dt)
                    op[dt * 16] = (__bf16)(acc[qq][dt][r] * sc);
            }
        }
    }
}

// ---------------- host launcher ----------------
extern "C" void kernel_launch(void* const* d_in, const int* in_sizes, int n_in,
                              void* d_out, int out_size, void* d_ws, size_t ws_size,
                              hipStream_t stream) {
    (void)in_sizes; (void)n_in; (void)out_size; (void)ws_size;
    const float* x    = (const float*)d_in[0];
    const float* wq   = (const float*)d_in[1];
    const float* wk   = (const float*)d_in[2];
    const float* wv   = (const float*)d_in[3];
    const float* wgq  = (const float*)d_in[4];
    const float* wgk  = (const float*)d_in[5];
    const float* wgv  = (const float*)d_in[6];
    const float* rout = (const float*)d_in[7];
    const float* glw  = (const float*)d_in[8];
    const float* grw  = (const float*)d_in[9];
    const float* wout = (const float*)d_in[10];

    char* p = (char*)d_ws;
    auto alloc = [&](size_t bytes) {
        char* r = p;
        p += (bytes + 255) & ~(size_t)255;
        return r;
    };
    __bf16* xb    = (__bf16*)alloc((size_t)BSROWS * DMODEL * 2);
    __bf16* QKVG  = (__bf16*)alloc((size_t)BSROWS * QKVN * 2);
    __bf16* VtG   = (__bf16*)alloc((size_t)BSROWS * DMODEL * 2);
    __bf16* wcatT = (__bf16*)alloc((size_t)QKVN * DMODEL * 2);
    __bf16* woutT = (__bf16*)alloc((size_t)DMODEL * DMODEL * 2);
    __bf16* wgkvT = (__bf16*)alloc((size_t)1024 * DMODEL * 2);   // [wgkT | wgvT]
    __bf16* routT = (__bf16*)alloc((size_t)DMODEL * LDIM * 2);
    __bf16* xpool = (__bf16*)alloc((size_t)256 * DMODEL * 2);    // padded to 256 rows
    __bf16* GKVb  = (__bf16*)alloc((size_t)256 * 1024 * 2);      // [GK | GV], 256-row tile
    __bf16* localg= (__bf16*)alloc((size_t)BSROWS * DMODEL * 2);
    float*  grbuf = (float*) alloc((size_t)BSROWS * 16 * 4);
    __bf16* remb  = (__bf16*)alloc((size_t)BSROWS * LDIM * 2);
    __bf16* outpre = xb; // alias: xb dead after fused projection

    TJ8 jobs;
    jobs.j[0] = {wq,   wcatT,                 DMODEL, DMODEL};
    jobs.j[1] = {wk,   wcatT + 1024 * DMODEL, DMODEL, DMODEL};
    jobs.j[2] = {wv,   wcatT + 2048 * DMODEL, DMODEL, DMODEL};
    jobs.j[3] = {wgq,  wcatT + 3072 * DMODEL, DMODEL, LDIM};
    jobs.j[4] = {wout, woutT,                 DMODEL, DMODEL};
    jobs.j[5] = {wgk,  wgkvT,                 DMODEL, LDIM};
    jobs.j[6] = {wgv,  wgkvT + 512 * DMODEL,  DMODEL, LDIM};
    jobs.j[7] = {rout, routT,                 LDIM,   DMODEL};

    // ONE prep dispatch: cvt+pool (512) + transposes (8192) + xpool pad-zero (32)
    prep_all<<<dim3(512 + 8192 + 32), 256, 0, stream>>>(x, xb, xpool, jobs);

    // fused [Q|K|V|GQ] projection + GKV side-row (y==14) via the 8-phase 256^2 GEMM;
    // V n-tiles land transposed in VtG (packed 8B stores)
    gemm256_bf16<<<dim3(32, 15), 512, 0, stream>>>(xb, wcatT, BSROWS, QKVN, DMODEL,
                                                   QKVG, VtG, xpool, wgkvT, GKVb);

    // single fused attention dispatch (local y=0..15, latent y=16..23)
    attn_fused<<<dim3(16, 24, 2), 256, 0, stream>>>(QKVG, VtG, GKVb, glw, grw,
                                                    localg, grbuf, remb);

    // trailing GEMMs on the tail-free 128x256 2-phase pipelined template (256 blocks each)
    gemm128n<true, true><<<dim3(64, 4), 512, 0, stream>>>(remb, routT, BSROWS, DMODEL, LDIM, outpre, nullptr, localg, grbuf);
    gemm128n<false, false><<<dim3(64, 4), 512, 0, stream>>>(outpre, woutT, BSROWS, DMODEL, DMODEL, nullptr, (float*)d_out, nullptr, nullptr);
}

// Round 14
// 169.795 us; speedup vs baseline: 1.0796x; 1.0796x over previous
//
#include <hip/hip_runtime.h>

#define AS1 __attribute__((address_space(1)))
#define AS3 __attribute__((address_space(3)))

typedef float    f32x4  __attribute__((ext_vector_type(4)));
typedef __bf16   bf16x8 __attribute__((ext_vector_type(8)));
typedef __bf16   bf16x4 __attribute__((ext_vector_type(4)));
typedef unsigned int u32x4 __attribute__((ext_vector_type(4)));

static constexpr int SEQ = 4096, NBATCH = 2, DMODEL = 1024, NHEADS = 16, HDIM = 64;
static constexpr int LHEADS = 8, LDIM = 512, NLAT = 64, WIN = 256;
static constexpr int BSROWS = NBATCH * SEQ; // 8192
static constexpr int QKVN = 3584;           // fused [Q|K|V|GQ] column count
static constexpr int KOFF = 1024, VOFF = 2048, GQOFF = 3072;

// ---------------- ONE prep dispatch: cvt+pool + 8 weight transposes + xpool pad-zero ----------------
struct TJ { const float* in; __bf16* out; int K; int N; };
struct TJ8 { TJ j[8]; };
__global__ __launch_bounds__(256) void prep_all(const float* __restrict__ x,
                                                __bf16* __restrict__ xb,
                                                __bf16* __restrict__ xpool, TJ8 jobs) {
    __shared__ float tbuf[32][33];
    int bid = blockIdx.x, t = threadIdx.x;
    if (bid < 512) {
        int bn = bid >> 2;
        int c  = (bid & 3) * 256 + t;
        const float* p = x + (size_t)bn * 64 * 1024 + c;
        __bf16* q = xb + (size_t)bn * 64 * 1024 + c;
        float s = 0.f;
        #pragma unroll 8
        for (int j = 0; j < 64; ++j) {
            float v = p[(size_t)j * 1024];
            q[(size_t)j * 1024] = (__bf16)v;
            s += v;
        }
        xpool[(size_t)bn * 1024 + c] = (__bf16)(s * 0.015625f);
    } else if (bid < 8704) {
        int ti = bid - 512;
        TJ jb = jobs.j[ti >> 10];
        int rem = ti & 1023;
        int k0 = (rem >> 5) * 32, n0 = (rem & 31) * 32;
        if (k0 >= jb.K || n0 >= jb.N) return;
        int tx = t & 31, ty = t >> 5; // (32, 8)
        #pragma unroll
        for (int i = ty; i < 32; i += 8) tbuf[i][tx] = jb.in[(size_t)(k0 + i) * jb.N + n0 + tx];
        __syncthreads();
        #pragma unroll
        for (int i = ty; i < 32; i += 8) jb.out[(size_t)(n0 + i) * jb.K + k0 + tx] = (__bf16)tbuf[tx][i];
    } else {
        int zi = bid - 8704;                 // 0..31
        size_t idx = ((size_t)zi * 256 + t) * 16;
        u32x4 z = {0u, 0u, 0u, 0u};
        *(u32x4*)(xpool + 128 * 1024 + idx)     = z;
        *(u32x4*)(xpool + 128 * 1024 + idx + 8) = z;
    }
}

// ---------------- 256x256 8-phase GEMM (T2+T3+T4+T5) + GKV side-row ----------------
// (verified r7-r13; conflict-free swizzle byte^=(row&7)<<4; fused V-transpose epilogue)
#define BAR() do { __builtin_amdgcn_sched_barrier(0); __builtin_amdgcn_s_barrier(); \
                   __builtin_amdgcn_sched_barrier(0); } while (0)
#define LGK0() do { asm volatile("s_waitcnt lgkmcnt(0)" ::: "memory"); \
                    __builtin_amdgcn_sched_barrier(0); } while (0)
#define VMC(n) do { asm volatile("s_waitcnt vmcnt(" #n ")" ::: "memory"); \
                    __builtin_amdgcn_sched_barrier(0); } while (0)
#define STG(gp, regionbase, rowbase, ktc) do { \
    int row_ = (rowbase) + (t >> 3); \
    int tc_ = (t & 7) ^ ((t >> 3) & 7); \
    __builtin_amdgcn_global_load_lds( \
        (const AS1 void*)((gp) + (size_t)row_ * K + (ktc) + tc_ * 8), \
        (AS3 void*)(lds + (regionbase) + (rowbase) * 128 + w * 1024), 16, 0, 0); \
} while (0)
#define LOADA(buf, qm) do { \
    _Pragma("unroll") for (int ai_ = 0; ai_ < 4; ++ai_) \
    _Pragma("unroll") for (int ks_ = 0; ks_ < 2; ++ks_) \
        a[ai_][ks_] = *(const bf16x8*)(lds + ((((buf) * 65536) + \
            (wm * 128 + (qm) * 64 + ai_ * 16 + l15) * 128 + ks_ * 64 + l4 * 16) ^ rswz)); \
} while (0)
#define LOADB2(buf, half) do { \
    _Pragma("unroll") for (int j_ = 0; j_ < 2; ++j_) \
    _Pragma("unroll") for (int ks_ = 0; ks_ < 2; ++ks_) \
        b2[j_][ks_] = *(const bf16x8*)(lds + ((((buf) * 65536 + 32768) + \
            (wn * 64 + ((half) * 2 + j_) * 16 + l15) * 128 + ks_ * 64 + l4 * 16) ^ rswz)); \
} while (0)
#define MFMA_PH(qm, half) do { \
    __builtin_amdgcn_s_setprio(1); \
    _Pragma("unroll") for (int ai_ = 0; ai_ < 4; ++ai_) \
    _Pragma("unroll") for (int j_ = 0; j_ < 2; ++j_) { \
        f32x4 c_ = acc[(qm) * 4 + ai_][(half) * 2 + j_]; \
        c_ = __builtin_amdgcn_mfma_f32_16x16x32_bf16(a[ai_][0], b2[j_][0], c_, 0, 0, 0); \
        c_ = __builtin_amdgcn_mfma_f32_16x16x32_bf16(a[ai_][1], b2[j_][1], c_, 0, 0, 0); \
        acc[(qm) * 4 + ai_][(half) * 2 + j_] = c_; \
    } \
    __builtin_amdgcn_s_setprio(0); \
} while (0)

__global__ __launch_bounds__(512, 2) void gemm256_bf16(
    const __bf16* __restrict__ A, const __bf16* __restrict__ Bt,
    int M, int N, int K, __bf16* __restrict__ outb, __bf16* __restrict__ Vt,
    const __bf16* __restrict__ A2, const __bf16* __restrict__ B2,
    __bf16* __restrict__ out2) {
    __shared__ char lds[131072];
    const int t = threadIdx.x, w = t >> 6, l = t & 63;
    const int wm = w >> 2, wn = w & 3;
    const int l15 = l & 15, l4 = l >> 4;
    const int NT = K >> 6;
    const int rswz = (l15 & 7) << 4;

    const __bf16* Ab; const __bf16* Bb; __bf16* outp; int Nout, m0, n0; bool doVt;
    if (blockIdx.y == 14) {
        if (blockIdx.x >= 4) return;      // whole block exits; no barrier hazard
        m0 = 0; n0 = blockIdx.x * 256;
        Ab = A2; Bb = B2 + (size_t)n0 * K;
        outp = out2; Nout = 1024; doVt = false;
    } else {
        m0 = blockIdx.x * 256; n0 = blockIdx.y * 256;
        Ab = A + (size_t)m0 * K; Bb = Bt + (size_t)n0 * K;
        outp = outb; Nout = N; doVt = (n0 >= VOFF && n0 < GQOFF);
    }

    f32x4 acc[8][4];
    #pragma unroll
    for (int i = 0; i < 8; ++i)
        #pragma unroll
        for (int j = 0; j < 4; ++j) acc[i][j] = (f32x4){0.f, 0.f, 0.f, 0.f};
    bf16x8 a[4][2], b2[2][2];

    STG(Ab, 0, 0, 0);        STG(Ab, 0, 128, 0);
    STG(Ab, 0, 64, 0);       STG(Ab, 0, 192, 0);
    STG(Bb, 32768, 0, 0);    STG(Bb, 32768, 64, 0);
    STG(Bb, 32768, 128, 0);  STG(Bb, 32768, 192, 0);
    STG(Ab, 65536, 0, 64);   STG(Ab, 65536, 128, 64);
    VMC(2); BAR();

    int it = 0;
    for (; it + 3 < NT; it += 2) {
        const int kt1 = (it + 1) << 6, kt2 = (it + 2) << 6, kt3 = (it + 3) << 6;
        LOADA(0, 0); LOADB2(0, 0);
        STG(Ab, 65536, 64, kt1); STG(Ab, 65536, 192, kt1);
        BAR(); LGK0(); MFMA_PH(0, 0); BAR();
        LOADB2(0, 1);
        STG(Bb, 98304, 0, kt1); STG(Bb, 98304, 64, kt1);
        BAR(); LGK0(); MFMA_PH(0, 1); BAR();
        LOADA(0, 1); LOADB2(0, 0);
        STG(Bb, 98304, 128, kt1); STG(Bb, 98304, 192, kt1);
        BAR(); LGK0(); MFMA_PH(1, 0); BAR();
        LOADB2(0, 1);
        STG(Ab, 0, 0, kt2); STG(Ab, 0, 128, kt2);
        BAR(); LGK0(); MFMA_PH(1, 1); VMC(2); BAR();
        LOADA(1, 0); LOADB2(1, 0);
        STG(Ab, 0, 64, kt2); STG(Ab, 0, 192, kt2);
        BAR(); LGK0(); MFMA_PH(0, 0); BAR();
        LOADB2(1, 1);
        STG(Bb, 32768, 0, kt2); STG(Bb, 32768, 64, kt2);
        BAR(); LGK0(); MFMA_PH(0, 1); BAR();
        LOADA(1, 1); LOADB2(1, 0);
        STG(Bb, 32768, 128, kt2); STG(Bb, 32768, 192, kt2);
        BAR(); LGK0(); MFMA_PH(1, 0); BAR();
        LOADB2(1, 1);
        STG(Ab, 65536, 0, kt3); STG(Ab, 65536, 128, kt3);
        BAR(); LGK0(); MFMA_PH(1, 1); VMC(2); BAR();
    }
    {
        const int kt1 = (it + 1) << 6;
        LOADA(0, 0); LOADB2(0, 0);
        STG(Ab, 65536, 64, kt1); STG(Ab, 65536, 192, kt1);
        BAR(); LGK0(); MFMA_PH(0, 0); BAR();
        LOADB2(0, 1);
        STG(Bb, 98304, 0, kt1); STG(Bb, 98304, 64, kt1);
        BAR(); LGK0(); MFMA_PH(0, 1); BAR();
        LOADA(0, 1); LOADB2(0, 0);
        STG(Bb, 98304, 128, kt1); STG(Bb, 98304, 192, kt1);
        BAR(); LGK0(); MFMA_PH(1, 0); BAR();
        LOADB2(0, 1);
        BAR(); LGK0(); MFMA_PH(1, 1); VMC(0); BAR();
        LOADA(1, 0); LOADB2(1, 0);
        BAR(); LGK0(); MFMA_PH(0, 0); BAR();
        LOADB2(1, 1);
        BAR(); LGK0(); MFMA_PH(0, 1); BAR();
        LOADA(1, 1); LOADB2(1, 0);
        BAR(); LGK0(); MFMA_PH(1, 0); BAR();
        LOADB2(1, 1);
        LGK0(); MFMA_PH(1, 1);
    }

    int cr = l4 * 4, cc = l15;
    if (doVt) {
        #pragma unroll
        for (int mi = 0; mi < 8; ++mi) {
            #pragma unroll
            for (int ni = 0; ni < 4; ++ni) {
                int vcol = (n0 - VOFF) + wn * 64 + ni * 16 + cc;
                int row0 = m0 + wm * 128 + mi * 16 + cr;
                int bb = row0 >> 12, ss = row0 & 4095;
                bf16x4 pk;
                #pragma unroll
                for (int r = 0; r < 4; ++r) pk[r] = (__bf16)acc[mi][ni][r];
                *(bf16x4*)(Vt + ((size_t)bb * DMODEL + vcol) * SEQ + ss) = pk;
            }
        }
    } else {
        #pragma unroll
        for (int mi = 0; mi < 8; ++mi) {
            #pragma unroll
            for (int ni = 0; ni < 4; ++ni) {
                int col = n0 + wn * 64 + ni * 16 + cc;
                #pragma unroll
                for (int r = 0; r < 4; ++r) {
                    int row = m0 + wm * 128 + mi * 16 + cr + r;
                    outp[(size_t)row * Nout + col] = (__bf16)acc[mi][ni][r];
                }
            }
        }
    }
}
#undef LOADA
#undef LOADB2
#undef MFMA_PH

// ---------------- 128x256-tile 2-phase/K-tile pipelined GEMM (tail-free for N=1024) ----------------
// r13: 2-phase (16 MFMA per barrier-pair, parity with gemm256's density); kept in r14
// to attribute the r13 regression (attn launch-bounds reverted separately).
#define LOADA3F(base) do { \
    _Pragma("unroll") for (int ai_ = 0; ai_ < 4; ++ai_) \
    _Pragma("unroll") for (int ks_ = 0; ks_ < 2; ++ks_) \
        a[ai_][ks_] = *(const bf16x8*)(lds + (((base) + \
            (wm2 * 64 + ai_ * 16 + l15) * 128 + ks_ * 64 + l4 * 16) ^ rswz)); \
} while (0)
#define LOADB3(base, nh) do { \
    _Pragma("unroll") for (int j_ = 0; j_ < 2; ++j_) \
    _Pragma("unroll") for (int ks_ = 0; ks_ < 2; ++ks_) \
        b2[j_][ks_] = *(const bf16x8*)(lds + (((base) + 16384 + \
            (wn * 64 + (nh) * 32 + j_ * 16 + l15) * 128 + ks_ * 64 + l4 * 16) ^ rswz)); \
} while (0)
#define MFMA_P3N(nh) do { \
    __builtin_amdgcn_s_setprio(1); \
    _Pragma("unroll") for (int ai_ = 0; ai_ < 4; ++ai_) \
    _Pragma("unroll") for (int j_ = 0; j_ < 2; ++j_) { \
        f32x4 c_ = acc[ai_][(nh) * 2 + j_]; \
        c_ = __builtin_amdgcn_mfma_f32_16x16x32_bf16(a[ai_][0], b2[j_][0], c_, 0, 0, 0); \
        c_ = __builtin_amdgcn_mfma_f32_16x16x32_bf16(a[ai_][1], b2[j_][1], c_, 0, 0, 0); \
        acc[ai_][(nh) * 2 + j_] = c_; \
    } \
    __builtin_amdgcn_s_setprio(0); \
} while (0)

template <bool EPI, bool OUTBF>
__global__ __launch_bounds__(512, 1) void gemm128n(
    const __bf16* __restrict__ A, const __bf16* __restrict__ Bt,
    int M, int N, int K,
    __bf16* __restrict__ outb, float* __restrict__ outf,
    const __bf16* __restrict__ lcl, const float* __restrict__ grb) {
    __shared__ char lds[147456];    // 3 x (16KB A + 32KB B)
    const int t = threadIdx.x, w = t >> 6, l = t & 63;
    const int wm2 = w >> 2, wn = w & 3;
    const int l15 = l & 15, l4 = l >> 4;
    const int m0 = blockIdx.x * 128, n0 = blockIdx.y * 256;
    const int NT = K >> 6;
    const int rswz = (l15 & 7) << 4;

    f32x4 acc[4][4];
    #pragma unroll
    for (int i = 0; i < 4; ++i)
        #pragma unroll
        for (int j = 0; j < 4; ++j) acc[i][j] = (f32x4){0.f, 0.f, 0.f, 0.f};
    bf16x8 a[4][2], b2[2][2];

    const __bf16* Ab = A + (size_t)m0 * K;
    const __bf16* Bb = Bt + (size_t)n0 * K;

    // prologue: stage tile0 -> buf0, tile1 -> buf1 (6 loads each); wait tile0 (vmcnt 6)
    STG(Ab, 0, 0, 0);      STG(Ab, 0, 64, 0);
    STG(Bb, 16384, 0, 0);  STG(Bb, 16384, 64, 0);
    STG(Bb, 16384, 128, 0); STG(Bb, 16384, 192, 0);
    STG(Ab, 49152, 0, 64);      STG(Ab, 49152, 64, 64);
    STG(Bb, 65536, 0, 64);  STG(Bb, 65536, 64, 64);
    STG(Bb, 65536, 128, 64); STG(Bb, 65536, 192, 64);
    VMC(6); BAR();

    int cb = 0, nb = 98304;   // current buf base; stage-target buf base ((it+2)%3)
    for (int it = 0; it + 2 < NT; ++it) {
        const int kt2 = (it + 2) << 6;
        // P1
        LOADA3F(cb); LOADB3(cb, 0);
        STG(Ab, nb, 0, kt2); STG(Ab, nb, 64, kt2); STG(Bb, nb + 16384, 0, kt2);
        BAR(); LGK0(); MFMA_P3N(0); BAR();
        // P2
        LOADB3(cb, 1);
        STG(Bb, nb + 16384, 64, kt2); STG(Bb, nb + 16384, 128, kt2); STG(Bb, nb + 16384, 192, kt2);
        BAR(); LGK0(); MFMA_P3N(1); VMC(6); BAR();
        cb = (cb == 98304) ? 0 : cb + 49152;
        nb = (nb == 98304) ? 0 : nb + 49152;
    }
    // tail tile NT-2: no stages; drain at P2
    {
        LOADA3F(cb); LOADB3(cb, 0);
        BAR(); LGK0(); MFMA_P3N(0); BAR();
        LOADB3(cb, 1);
        BAR(); LGK0(); MFMA_P3N(1); VMC(0); BAR();
        cb = (cb == 98304) ? 0 : cb + 49152;
    }
    // tail tile NT-1
    {
        LOADA3F(cb); LOADB3(cb, 0);
        BAR(); LGK0(); MFMA_P3N(0); BAR();
        LOADB3(cb, 1);
        LGK0(); MFMA_P3N(1);
    }

    // epilogue (verified C/D mapping + EPI combine)
    int cr = l4 * 4, cc = l15;
    #pragma unroll
    for (int mi = 0; mi < 4; ++mi) {
        #pragma unroll
        for (int ni = 0; ni < 4; ++ni) {
            int col = n0 + wn * 64 + ni * 16 + cc;
            #pragma unroll
            for (int r = 0; r < 4; ++r) {
                int row = m0 + wm2 * 64 + mi * 16 + cr + r;
                float v = acc[mi][ni][r];
                if constexpr (EPI) {
                    v = (float)lcl[(size_t)row * 1024 + col] +
                        grb[(size_t)row * 16 + (col >> 6)] * v;
                }
                if constexpr (OUTBF) outb[(size_t)row * N + col] = (__bf16)v;
                else                 outf[(size_t)row * N + col] = v;
            }
        }
    }
}
#undef BAR
#undef LGK0
#undef VMC
#undef STG
#undef LOADA3F
#undef LOADB3
#undef MFMA_P3N

// ---------------- fused attention: ONE dispatch for local + latent ----------------
// r14: REVERTED to __launch_bounds__(256, 2) — the (256,3) cap (~170 VGPR) forced
// scratch spills on the ~190-VGPR local branch; r13's regression attributed here.
__global__ __launch_bounds__(256, 2) void attn_fused(
    const __bf16* __restrict__ QKVG, const __bf16* __restrict__ Vt,
    const __bf16* __restrict__ GKV,
    const float* __restrict__ glw, const float* __restrict__ grw,
    __bf16* __restrict__ outl, float* __restrict__ grbuf,
    __bf16* __restrict__ rem) {
    __shared__ alignas(16) char smem[32768];
    int t = threadIdx.x, w = t >> 6, l = t & 63;
    int l15 = l & 15, l4 = l >> 4;
    int b = blockIdx.z;
    f32x4 zero = {0.f, 0.f, 0.f, 0.f};

    if (blockIdx.y < 16) {
        // ======== local sliding-window attention (K-direct + V-direct) ========
        int blk = blockIdx.x, h = blockIdx.y;
        char* sPb = smem;

        bf16x8 qf[4][2];
        long qbase = (long)b * SEQ + blk * 256 + 64 * w;
        #pragma unroll
        for (int qq = 0; qq < 4; ++qq)
            #pragma unroll
            for (int ks = 0; ks < 2; ++ks)
                qf[qq][ks] = *(const bf16x8*)(QKVG + (size_t)(qbase + qq * 16 + l15) * QKVN
                                              + h * 64 + ks * 32 + l4 * 8);

        float dlp[4], drp[4];
        #pragma unroll
        for (int qq = 0; qq < 4; ++qq) {
            float dl = 0.f, dr = 0.f;
            #pragma unroll
            for (int ks = 0; ks < 2; ++ks) {
                const float* gp = glw + h * 64 + ks * 32 + l4 * 8;
                const float* rp = grw + h * 64 + ks * 32 + l4 * 8;
                #pragma unroll
                for (int j = 0; j < 8; ++j) {
                    float qv = (float)qf[qq][ks][j];
                    dl += qv * gp[j];
                    dr += qv * rp[j];
                }
            }
            dlp[qq] = dl; drp[qq] = dr;
        }
        float glv[4], grv[4];
        #pragma unroll
        for (int qq = 0; qq < 4; ++qq) {
            float dl = dlp[qq] + __shfl_xor(dlp[qq], 16);
            dl += __shfl_xor(dl, 32);
            float dr = drp[qq] + __shfl_xor(drp[qq], 16);
            dr += __shfl_xor(dr, 32);
            glv[qq] = 1.f / (1.f + __expf(-dl));
            grv[qq] = 1.f / (1.f + __expf(-dr));
        }
        if (l4 == 0) {
            #pragma unroll
            for (int qq = 0; qq < 4; ++qq)
                grbuf[(size_t)(qbase + qq * 16 + l15) * 16 + h] = grv[qq];
        }

        f32x4 acc[4][4];
        #pragma unroll
        for (int a2 = 0; a2 < 4; ++a2)
            #pragma unroll
            for (int d = 0; d < 4; ++d) acc[a2][d] = zero;
        float psum[4] = {0.f, 0.f, 0.f, 0.f};

        char* sPw = sPb + w * 4096;
        int nsteps = (w == 3) ? 10 : 11;
        int kk0 = 64 * w;
        long g0 = (long)b * SEQ + (long)(blk - 1) * WIN;
        const __bf16* vtb = Vt + (size_t)b * DMODEL * SEQ + (size_t)(h * 64) * SEQ;

        for (int stp = 0; stp < nsteps; ++stp) {
            int kk = kk0 + 32 * stp;
            f32x4 sacc[2][4];
            #pragma unroll
            for (int kt2 = 0; kt2 < 2; ++kt2) {
                int krow = kk + kt2 * 16 + l15;
                long kgrow = g0 + krow;
                if (blk == 0 && krow < 256) kgrow = (long)b * SEQ;  // clamp; masked anyway
                const __bf16* kp = QKVG + (size_t)kgrow * QKVN + KOFF + h * 64;
                bf16x8 af0 = *(const bf16x8*)(kp + l4 * 8);
                bf16x8 af1 = *(const bf16x8*)(kp + 32 + l4 * 8);
                #pragma unroll
                for (int qq = 0; qq < 4; ++qq) {
                    f32x4 s = __builtin_amdgcn_mfma_f32_16x16x32_bf16(af0, qf[qq][0], zero, 0, 0, 0);
                    sacc[kt2][qq] = __builtin_amdgcn_mfma_f32_16x16x32_bf16(af1, qf[qq][1], s, 0, 0, 0);
                }
            }
            #pragma unroll
            for (int qq = 0; qq < 4; ++qq) {
                int qloc = 64 * w + qq * 16 + l15;
                int prow = qq * 16 + l15;
                #pragma unroll
                for (int kt2 = 0; kt2 < 2; ++kt2) {
                    int jb = kk + kt2 * 16 + l4 * 4;
                    bf16x4 pb;
                    #pragma unroll
                    for (int r = 0; r < 4; ++r) {
                        int jw = jb + r;
                        bool act = (jw > qloc) && (jw <= qloc + 256) && (blk > 0 || jw >= 256);
                        float pv = act ? __expf(sacc[kt2][qq][r] * 0.125f) : 0.f;
                        psum[qq] += pv;
                        pb[r] = (__bf16)pv;
                    }
                    *(bf16x4*)(sPw + prow * 64 + ((kt2 * 32 + l4 * 8) ^ ((prow & 3) << 4))) = pb;
                }
            }
            int kglob = (blk - 1) * WIN + kk + l4 * 8;
            if (kglob < 0) kglob = 0;
            bf16x8 pa[4], bv[4];
            #pragma unroll
            for (int qq = 0; qq < 4; ++qq) {
                int prow = qq * 16 + l15;
                pa[qq] = *(const bf16x8*)(sPw + prow * 64 + ((l4 * 16) ^ ((prow & 3) << 4)));
            }
            #pragma unroll
            for (int dt = 0; dt < 4; ++dt)
                bv[dt] = *(const bf16x8*)(vtb + (size_t)(dt * 16 + l15) * SEQ + kglob);
            #pragma unroll
            for (int qq = 0; qq < 4; ++qq)
                #pragma unroll
                for (int dt = 0; dt < 4; ++dt)
                    acc[qq][dt] = __builtin_amdgcn_mfma_f32_16x16x32_bf16(pa[qq], bv[dt], acc[qq][dt], 0, 0, 0);
        }

        float cmb[4];
        #pragma unroll
        for (int qq = 0; qq < 4; ++qq) {
            float s = psum[qq] + __shfl_xor(psum[qq], 16);
            s += __shfl_xor(s, 32);
            cmb[qq] = glv[qq] / s;
        }
        #pragma unroll
        for (int qq = 0; qq < 4; ++qq) {
            #pragma unroll
            for (int r = 0; r < 4; ++r) {
                float sc = __shfl(cmb[qq], l4 * 4 + r, 64);
                size_t row = (size_t)(qbase + qq * 16 + l4 * 4 + r);
                __bf16* op = outl + row * DMODEL + h * 64 + l15;
                #pragma unroll
                for (int dt = 0; dt < 4; ++dt)
                    op[dt * 16] = (__bf16)(acc[qq][dt][r] * sc);
            }
        }
    } else {
        // ======== latent (remote) attention (verified r4-r13; GKV merged stride 1024) ========
        int sb = blockIdx.x, lh = blockIdx.y - 16;
        char* sK  = smem;
        char* sVt = smem + 8192;
        char* sPb = smem + 16384;

        bf16x8 qf[4][2];
        long qbase = (long)b * SEQ + sb * 256 + 64 * w;
        #pragma unroll
        for (int qq = 0; qq < 4; ++qq)
            #pragma unroll
            for (int ks = 0; ks < 2; ++ks)
                qf[qq][ks] = *(const bf16x8*)(QKVG + (size_t)(qbase + qq * 16 + l15) * QKVN
                                              + GQOFF + lh * 64 + ks * 32 + l4 * 8);

        #pragma unroll
        for (int rep = 0; rep < 2; ++rep) {
            int ci = rep * 256 + t;
            int row = ci >> 3, c8 = (ci & 7) * 8;
            u32x4 kv = *(const u32x4*)(GKV + (size_t)(b * 64 + row) * 1024 + lh * 64 + c8);
            *(u32x4*)(sK + row * 128 + ((c8 * 2) ^ ((row & 7) << 4))) = kv;
        }
        #pragma unroll
        for (int rep = 0; rep < 16; ++rep) {
            int idx = rep * 256 + t;
            int d = idx & 63, n = idx >> 6;
            __bf16 v = GKV[(size_t)(b * 64 + n) * 1024 + 512 + lh * 64 + d];
            *(__bf16*)(sVt + d * 128 + ((n * 2) ^ ((d & 7) << 4))) = v;
        }
        __syncthreads();

        f32x4 acc[4][4];
        #pragma unroll
        for (int a2 = 0; a2 < 4; ++a2)
            #pragma unroll
            for (int d = 0; d < 4; ++d) acc[a2][d] = zero;
        float psum[4] = {0.f, 0.f, 0.f, 0.f};

        char* sPw = sPb + w * 4096;
        int qloc0 = sb * 256 + 64 * w;

        #pragma unroll
        for (int stp = 0; stp < 2; ++stp) {
            int kk = 32 * stp;
            f32x4 sacc[2][4];
            #pragma unroll
            for (int kt2 = 0; kt2 < 2; ++kt2) {
                int krow = kk + kt2 * 16 + l15;
                int swz = (krow & 7) << 4;
                bf16x8 af0 = *(const bf16x8*)(sK + krow * 128 + ((l4 * 16) ^ swz));
                bf16x8 af1 = *(const bf16x8*)(sK + krow * 128 + ((64 + l4 * 16) ^ swz));
                #pragma unroll
                for (int qq = 0; qq < 4; ++qq) {
                    f32x4 s = __builtin_amdgcn_mfma_f32_16x16x32_bf16(af0, qf[qq][0], zero, 0, 0, 0);
                    sacc[kt2][qq] = __builtin_amdgcn_mfma_f32_16x16x32_bf16(af1, qf[qq][1], s, 0, 0, 0);
                }
            }
            #pragma unroll
            for (int qq = 0; qq < 4; ++qq) {
                int qdv = (qloc0 + qq * 16 + l15) >> 6;
                int prow = qq * 16 + l15;
                #pragma unroll
                for (int kt2 = 0; kt2 < 2; ++kt2) {
                    int nb = kk + kt2 * 16 + l4 * 4;
                    bf16x4 pb;
                    #pragma unroll
                    for (int r = 0; r < 4; ++r) {
                        int n = nb + r;
                        float pv = (n <= qdv) ? __expf(sacc[kt2][qq][r] * 0.125f) : 0.f;
                        psum[qq] += pv;
                        pb[r] = (__bf16)pv;
                    }
                    *(bf16x4*)(sPw + prow * 64 + ((kt2 * 32 + l4 * 8) ^ ((prow & 3) << 4))) = pb;
                }
            }
            bf16x8 pa[4], bv[4];
            #pragma unroll
            for (int qq = 0; qq < 4; ++qq) {
                int prow = qq * 16 + l15;
                pa[qq] = *(const bf16x8*)(sPw + prow * 64 + ((l4 * 16) ^ ((prow & 3) << 4)));
            }
            #pragma unroll
            for (int dt = 0; dt < 4; ++dt) {
                int d = dt * 16 + l15;
                bv[dt] = *(const bf16x8*)(sVt + d * 128 + ((kk * 2 + l4 * 16) ^ ((d & 7) << 4)));
            }
            #pragma unroll
            for (int qq = 0; qq < 4; ++qq)
                #pragma unroll
                for (int dt = 0; dt < 4; ++dt)
                    acc[qq][dt] = __builtin_amdgcn_mfma_f32_16x16x32_bf16(pa[qq], bv[dt], acc[qq][dt], 0, 0, 0);
        }

        float cmb[4];
        #pragma unroll
        for (int qq = 0; qq < 4; ++qq) {
            float s = psum[qq] + __shfl_xor(psum[qq], 16);
            s += __shfl_xor(s, 32);
            cmb[qq] = 1.f / s;
        }
        #pragma unroll
        for (int qq = 0; qq < 4; ++qq) {
            #pragma unroll
            for (int r = 0; r < 4; ++r) {
                float sc = __shfl(cmb[qq], l4 * 4 + r, 64);
                size_t row = (size_t)(qbase + qq * 16 + l4 * 4 + r);
                __bf16* op = rem + row * LDIM + lh * 64 + l15;
                #pragma unroll
                for (int dt = 0; dt < 4; ++dt)
                    op[dt * 16] = (__bf16)(acc[qq][dt][r] * sc);
            }
        }
    }
}

// ---------------- host launcher ----------------
extern "C" void kernel_launch(void* const* d_in, const int* in_sizes, int n_in,
                              void* d_out, int out_size, void* d_ws, size_t ws_size,
                              hipStream_t stream) {
    (void)in_sizes; (void)n_in; (void)out_size; (void)ws_size;
    const float* x    = (const float*)d_in[0];
    const float* wq   = (const float*)d_in[1];
    const float* wk   = (const float*)d_in[2];
    const float* wv   = (const float*)d_in[3];
    const float* wgq  = (const float*)d_in[4];
    const float* wgk  = (const float*)d_in[5];
    const float* wgv  = (const float*)d_in[6];
    const float* rout = (const float*)d_in[7];
    const float* glw  = (const float*)d_in[8];
    const float* grw  = (const float*)d_in[9];
    const float* wout = (const float*)d_in[10];

    char* p = (char*)d_ws;
    auto alloc = [&](size_t bytes) {
        char* r = p;
        p += (bytes + 255) & ~(size_t)255;
        return r;
    };
    __bf16* xb    = (__bf16*)alloc((size_t)BSROWS * DMODEL * 2);
    __bf16* QKVG  = (__bf16*)alloc((size_t)BSROWS * QKVN * 2);
    __bf16* VtG   = (__bf16*)alloc((size_t)BSROWS * DMODEL * 2);
    __bf16* wcatT = (__bf16*)alloc((size_t)QKVN * DMODEL * 2);
    __bf16* woutT = (__bf16*)alloc((size_t)DMODEL * DMODEL * 2);
    __bf16* wgkvT = (__bf16*)alloc((size_t)1024 * DMODEL * 2);   // [wgkT | wgvT]
    __bf16* routT = (__bf16*)alloc((size_t)DMODEL * LDIM * 2);
    __bf16* xpool = (__bf16*)alloc((size_t)256 * DMODEL * 2);    // padded to 256 rows
    __bf16* GKVb  = (__bf16*)alloc((size_t)256 * 1024 * 2);      // [GK | GV], 256-row tile
    __bf16* localg= (__bf16*)alloc((size_t)BSROWS * DMODEL * 2);
    float*  grbuf = (float*) alloc((size_t)BSROWS * 16 * 4);
    __bf16* remb  = (__bf16*)alloc((size_t)BSROWS * LDIM * 2);
    __bf16* outpre = xb; // alias: xb dead after fused projection

    TJ8 jobs;
    jobs.j[0] = {wq,   wcatT,                 DMODEL, DMODEL};
    jobs.j[1] = {wk,   wcatT + 1024 * DMODEL, DMODEL, DMODEL};
    jobs.j[2] = {wv,   wcatT + 2048 * DMODEL, DMODEL, DMODEL};
    jobs.j[3] = {wgq,  wcatT + 3072 * DMODEL, DMODEL, LDIM};
    jobs.j[4] = {wout, woutT,                 DMODEL, DMODEL};
    jobs.j[5] = {wgk,  wgkvT,                 DMODEL, LDIM};
    jobs.j[6] = {wgv,  wgkvT + 512 * DMODEL,  DMODEL, LDIM};
    jobs.j[7] = {rout, routT,                 LDIM,   DMODEL};

    // ONE prep dispatch: cvt+pool (512) + transposes (8192) + xpool pad-zero (32)
    prep_all<<<dim3(512 + 8192 + 32), 256, 0, stream>>>(x, xb, xpool, jobs);

    // fused [Q|K|V|GQ] projection + GKV side-row (y==14) via the 8-phase 256^2 GEMM;
    // V n-tiles land transposed in VtG (packed 8B stores)
    gemm256_bf16<<<dim3(32, 15), 512, 0, stream>>>(xb, wcatT, BSROWS, QKVN, DMODEL,
                                                   QKVG, VtG, xpool, wgkvT, GKVb);

    // single fused attention dispatch (local y=0..15, latent y=16..23)
    attn_fused<<<dim3(16, 24, 2), 256, 0, stream>>>(QKVG, VtG, GKVb, glw, grw,
                                                    localg, grbuf, remb);

    // trailing GEMMs on the tail-free 128x256 2-phase pipelined template (256 blocks each)
    gemm128n<true, true><<<dim3(64, 4), 512, 0, stream>>>(remb, routT, BSROWS, DMODEL, LDIM, outpre, nullptr, localg, grbuf);
    gemm128n<false, false><<<dim3(64, 4), 512, 0, stream>>>(outpre, woutT, BSROWS, DMODEL, DMODEL, nullptr, (float*)d_out, nullptr, nullptr);
}